// Round 9
// baseline (947.416 us; speedup 1.0000x reference)
//
#include <hip/hip_runtime.h>
#include <hip/hip_cooperative_groups.h>
#include <stdint.h>

// VoxelLayer: JAX voxel-grid downsample ×2, bit-exact Threefry-2x32
// (partitionable) sampling. Round 9: cooperative mega-kernel with CUSTOM
// hierarchical grid barrier (round 8's gg.sync was ~110us/sync). x read
// once (chunk held in regs across barrier); accum2 bins sample1's gathered
// centroids from regs; chunk-local compaction + prefix-search samplers.

typedef unsigned int u32;
typedef unsigned long long u64;

struct KeyArr { uint32_t k0[16]; uint32_t k1[16]; };

__host__ __device__ inline void tf2x32(uint32_t k0, uint32_t k1,
                                       uint32_t c0, uint32_t c1,
                                       uint32_t& o0, uint32_t& o1) {
  const uint32_t ks0 = k0, ks1 = k1, ks2 = k0 ^ k1 ^ 0x1BD11BDAu;
  uint32_t x0 = c0 + ks0, x1 = c1 + ks1;
#define TF_R(r) { x0 += x1; x1 = (x1 << (r)) | (x1 >> (32 - (r))); x1 ^= x0; }
  TF_R(13) TF_R(15) TF_R(26) TF_R(6)
  x0 += ks1; x1 += ks2 + 1u;
  TF_R(17) TF_R(29) TF_R(16) TF_R(24)
  x0 += ks2; x1 += ks0 + 2u;
  TF_R(13) TF_R(15) TF_R(26) TF_R(6)
  x0 += ks0; x1 += ks1 + 3u;
  TF_R(17) TF_R(29) TF_R(16) TF_R(24)
  x0 += ks1; x1 += ks2 + 4u;
  TF_R(13) TF_R(15) TF_R(26) TF_R(6)
  x0 += ks2; x1 += ks0 + 5u;
#undef TF_R
  o0 = x0; o1 = x1;
}

#define MN1 262144
#define ML1 131072
#define ML2 65536
#define MG1 8000
#define MG2 1000

// ---- custom grid barrier: 16 leaves (64B apart) + root + gen ----
__device__ __forceinline__ void gridbar(u32* bar) {
  __syncthreads();
  __threadfence();
  if (threadIdx.x == 0) {
    u32* leaf = bar + ((blockIdx.x >> 4) << 4);
    u32* root = bar + 320;
    u32* gen = bar + 384;
    u32 g = __hip_atomic_load(gen, __ATOMIC_RELAXED, __HIP_MEMORY_SCOPE_AGENT);
    u32 lo = __hip_atomic_fetch_add(leaf, 1u, __ATOMIC_ACQ_REL,
                                    __HIP_MEMORY_SCOPE_AGENT);
    bool done = false;
    if (lo == 15u) {
      u32 ro = __hip_atomic_fetch_add(root, 1u, __ATOMIC_ACQ_REL,
                                      __HIP_MEMORY_SCOPE_AGENT);
      if (ro == 15u) {  // global last: reset counters, then release
        for (int i = 0; i < 16; ++i)
          __hip_atomic_store(bar + i * 16, 0u, __ATOMIC_RELAXED,
                             __HIP_MEMORY_SCOPE_AGENT);
        __hip_atomic_store(root, 0u, __ATOMIC_RELAXED,
                           __HIP_MEMORY_SCOPE_AGENT);
        __hip_atomic_fetch_add(gen, 1u, __ATOMIC_RELEASE,
                               __HIP_MEMORY_SCOPE_AGENT);
        done = true;
      }
    }
    if (!done) {
      while (__hip_atomic_load(gen, __ATOMIC_ACQUIRE,
                               __HIP_MEMORY_SCOPE_AGENT) == g)
        __builtin_amdgcn_s_sleep(2);
    }
  }
  __syncthreads();
  __threadfence();
}

__device__ __forceinline__ void bin1(float px, float py, float pz, float m0,
                                     float m1, float m2, float vox, int S,
                                     u64* lA, u64* lB) {
  int v0 = (int)floorf((px - m0) / vox);
  int v1 = (int)floorf((py - m1) / vox);
  int v2 = (int)floorf((pz - m2) / vox);
  int lin = (v0 * S + v1) * S + v2;
  u32 qx = (u32)(px * 1048576.0f);
  u32 qy = (u32)(py * 1048576.0f);
  u32 qz = (u32)(pz * 1048576.0f);
  atomicAdd(&lA[lin], ((u64)qy << 32) | (u64)qx);
  atomicAdd(&lB[lin], (1ull << 32) | (u64)qz);
}

// =================== cooperative mega-kernel v2 ===================
__global__ __launch_bounds__(1024) void mega2(
    const float* __restrict__ x, float* __restrict__ out,
    u64* __restrict__ Ap, u64* __restrict__ Bp, float4* __restrict__ mc1,
    float4* __restrict__ mc2, float* __restrict__ pmin1,
    float* __restrict__ pmin2, u32* __restrict__ ccnt1,
    u32* __restrict__ ccnt2, u32* __restrict__ bar, KeyArr keys1,
    KeyArr keys2) {
  extern __shared__ u64 lds[];  // 16000 u64 = 128000 B
  __shared__ float s_tree[48];
  __shared__ float s_m[3];
  __shared__ u32 s_w[32];
  const int k = blockIdx.x, b = k >> 4, c = k & 15;
  const int tid = threadIdx.x, lane = tid & 63, wid = tid >> 6;

  // ---- P0: load chunk (16 pts/thread) once; per-row block min ----
  const float* bx = x + (size_t)b * 3 * MN1;
  const float4* r0 = (const float4*)bx + c * 4096;
  const float4* r1 = (const float4*)(bx + MN1) + c * 4096;
  const float4* r2 = (const float4*)(bx + 2 * MN1) + c * 4096;
  float4 X0 = r0[tid], X1 = r0[tid + 1024], X2 = r0[tid + 2048],
         X3 = r0[tid + 3072];
  float4 Y0 = r1[tid], Y1 = r1[tid + 1024], Y2 = r1[tid + 2048],
         Y3 = r1[tid + 3072];
  float4 Z0 = r2[tid], Z1 = r2[tid + 1024], Z2 = r2[tid + 2048],
         Z3 = r2[tid + 3072];
  {
#define MIN4(v) fminf(fminf(v.x, v.y), fminf(v.z, v.w))
    float mx = fminf(fminf(MIN4(X0), MIN4(X1)), fminf(MIN4(X2), MIN4(X3)));
    float my = fminf(fminf(MIN4(Y0), MIN4(Y1)), fminf(MIN4(Y2), MIN4(Y3)));
    float mz = fminf(fminf(MIN4(Z0), MIN4(Z1)), fminf(MIN4(Z2), MIN4(Z3)));
#undef MIN4
    for (int off = 32; off; off >>= 1) {
      mx = fminf(mx, __shfl_down(mx, off, 64));
      my = fminf(my, __shfl_down(my, off, 64));
      mz = fminf(mz, __shfl_down(mz, off, 64));
    }
    if (lane == 0) {
      s_tree[0 * 16 + wid] = mx;
      s_tree[1 * 16 + wid] = my;
      s_tree[2 * 16 + wid] = mz;
    }
    // zero layer-1 hist while mins land
    for (int i = tid; i < 2 * MG1; i += 1024) lds[i] = 0ull;
    __syncthreads();
    if (tid < 3) {
      float v = s_tree[tid * 16];
      for (int i = 1; i < 16; ++i) v = fminf(v, s_tree[tid * 16 + i]);
      pmin1[(b * 3 + tid) * 16 + c] = v;
    }
  }
  gridbar(bar);

  // ---- P1: global min; bin 16 held points; write partial slice c ----
  {
    if (tid < 3) {
      float v = pmin1[(b * 3 + tid) * 16];
      for (int i = 1; i < 16; ++i)
        v = fminf(v, pmin1[(b * 3 + tid) * 16 + i]);
      s_m[tid] = v;
    }
    __syncthreads();
    float m0 = s_m[0], m1 = s_m[1], m2 = s_m[2];
    u64* lA = lds;
    u64* lB = lds + MG1;
#define B4(X, Y, Z) \
    bin1(X.x, Y.x, Z.x, m0, m1, m2, 0.05f, 20, lA, lB); \
    bin1(X.y, Y.y, Z.y, m0, m1, m2, 0.05f, 20, lA, lB); \
    bin1(X.z, Y.z, Z.z, m0, m1, m2, 0.05f, 20, lA, lB); \
    bin1(X.w, Y.w, Z.w, m0, m1, m2, 0.05f, 20, lA, lB);
    B4(X0, Y0, Z0) B4(X1, Y1, Z1) B4(X2, Y2, Z2) B4(X3, Y3, Z3)
#undef B4
    __syncthreads();
    u64* gA = Ap + ((size_t)c * 16 + b) * MG1;
    u64* gB = Bp + ((size_t)c * 16 + b) * MG1;
    for (int cell = tid; cell < MG1; cell += 1024) {
      gA[cell] = lds[cell];
      gB[cell] = lds[MG1 + cell];
    }
  }
  gridbar(bar);

  // ---- P2: reduce 16 partials for cells [c*500,+500); chunk compact ----
  {
    float4 cv = make_float4(0.f, 0.f, 0.f, 0.f);
    bool occ = false;
    if (tid < 500) {
      int cell = c * 500 + tid;
      u64 A = 0ull, Bv = 0ull;
#pragma unroll
      for (int p = 0; p < 16; ++p) {
        size_t o = ((size_t)p * 16 + b) * MG1 + cell;
        A += Ap[o];
        Bv += Bp[o];
      }
      u32 cnt = (u32)(Bv >> 32);
      if (cnt) {
        double inv = 1.0 / (1048576.0 * (double)cnt);
        cv.x = (float)((double)(u32)A * inv);
        cv.y = (float)((double)(u32)(A >> 32) * inv);
        cv.z = (float)((double)(u32)Bv * inv);
        occ = true;
      }
    }
    u64 mask = __ballot(occ);
    u32 wpre = (u32)__popcll(mask & ((1ull << lane) - 1ull));
    if (lane == 0) s_w[wid] = (u32)__popcll(mask);
    __syncthreads();
    if (tid == 0) {
      u32 s = 0;
      for (int w = 0; w < 16; ++w) { u32 t = s_w[w]; s_w[16 + w] = s; s += t; }
      ccnt1[b * 16 + c] = s;
    }
    __syncthreads();
    if (occ) mc1[((size_t)b * 16 + c) * 500 + s_w[16 + wid] + wpre] = cv;
  }
  gridbar(bar);

  // ---- P3: sample layer 1 (8/thread, prefix-search), out1, pmin2 ----
  float4 mm0, mm1, mm2, mm3, mm4, mm5, mm6, mm7;
  {
    u32 pre[17];
    pre[0] = 0;
#pragma unroll
    for (int j = 0; j < 16; ++j) pre[j + 1] = pre[j] + ccnt1[b * 16 + j];
    u32 nv = pre[16];
    float fnv = (float)nv;
    int nvm1 = (int)nv - 1;
    uint32_t K0 = keys1.k0[b], K1 = keys1.k1[b];
    int l0 = c * 8192 + tid * 8;
    float4 mm[8];
#pragma unroll
    for (int j = 0; j < 8; ++j) {
      uint32_t w0, w1;
      tf2x32(K0, K1, 0u, (uint32_t)(l0 + j), w0, w1);
      uint32_t bits = w0 ^ w1;  // partitionable fold
      float u = __uint_as_float((bits >> 9) | 0x3F800000u) - 1.0f;
      int idx = (int)(u * fnv);
      if (idx > nvm1) idx = nvm1;
      u32 uidx = (u32)idx;
      int ch = 0, base = 0;
#pragma unroll
      for (int q = 1; q < 16; ++q) {
        u32 pq = pre[q];
        if (uidx >= pq) { ch = q; base = (int)pq; }
      }
      mm[j] = mc1[((size_t)b * 16 + ch) * 500 + (idx - base)];
    }
    float* orow = out + ((size_t)b * 3 + 0) * ML1 + l0;
    *(float4*)orow = make_float4(mm[0].x, mm[1].x, mm[2].x, mm[3].x);
    *(float4*)(orow + 4) = make_float4(mm[4].x, mm[5].x, mm[6].x, mm[7].x);
    orow = out + ((size_t)b * 3 + 1) * ML1 + l0;
    *(float4*)orow = make_float4(mm[0].y, mm[1].y, mm[2].y, mm[3].y);
    *(float4*)(orow + 4) = make_float4(mm[4].y, mm[5].y, mm[6].y, mm[7].y);
    orow = out + ((size_t)b * 3 + 2) * ML1 + l0;
    *(float4*)orow = make_float4(mm[0].z, mm[1].z, mm[2].z, mm[3].z);
    *(float4*)(orow + 4) = make_float4(mm[4].z, mm[5].z, mm[6].z, mm[7].z);
    float ax = fminf(fminf(fminf(mm[0].x, mm[1].x), fminf(mm[2].x, mm[3].x)),
                     fminf(fminf(mm[4].x, mm[5].x), fminf(mm[6].x, mm[7].x)));
    float ay = fminf(fminf(fminf(mm[0].y, mm[1].y), fminf(mm[2].y, mm[3].y)),
                     fminf(fminf(mm[4].y, mm[5].y), fminf(mm[6].y, mm[7].y)));
    float az = fminf(fminf(fminf(mm[0].z, mm[1].z), fminf(mm[2].z, mm[3].z)),
                     fminf(fminf(mm[4].z, mm[5].z), fminf(mm[6].z, mm[7].z)));
    for (int off = 32; off; off >>= 1) {
      ax = fminf(ax, __shfl_down(ax, off, 64));
      ay = fminf(ay, __shfl_down(ay, off, 64));
      az = fminf(az, __shfl_down(az, off, 64));
    }
    if (lane == 0) {
      s_tree[0 * 16 + wid] = ax;
      s_tree[1 * 16 + wid] = ay;
      s_tree[2 * 16 + wid] = az;
    }
    // zero layer-2 hist
    for (int i = tid; i < 2 * MG2; i += 1024) lds[i] = 0ull;
    __syncthreads();
    if (tid < 3) {
      float v = s_tree[tid * 16];
      for (int i = 1; i < 16; ++i) v = fminf(v, s_tree[tid * 16 + i]);
      pmin2[(b * 3 + tid) * 16 + c] = v;
    }
    mm0 = mm[0]; mm1 = mm[1]; mm2 = mm[2]; mm3 = mm[3];
    mm4 = mm[4]; mm5 = mm[5]; mm6 = mm[6]; mm7 = mm[7];
  }
  gridbar(bar);

  // ---- P4: global min2; bin held 8 centroids; write partial2 slice ----
  {
    if (tid < 3) {
      float v = pmin2[(b * 3 + tid) * 16];
      for (int i = 1; i < 16; ++i)
        v = fminf(v, pmin2[(b * 3 + tid) * 16 + i]);
      s_m[tid] = v;
    }
    __syncthreads();
    float m0 = s_m[0], m1 = s_m[1], m2 = s_m[2];
    u64* lA = lds;
    u64* lB = lds + MG2;
    bin1(mm0.x, mm0.y, mm0.z, m0, m1, m2, 0.1f, 10, lA, lB);
    bin1(mm1.x, mm1.y, mm1.z, m0, m1, m2, 0.1f, 10, lA, lB);
    bin1(mm2.x, mm2.y, mm2.z, m0, m1, m2, 0.1f, 10, lA, lB);
    bin1(mm3.x, mm3.y, mm3.z, m0, m1, m2, 0.1f, 10, lA, lB);
    bin1(mm4.x, mm4.y, mm4.z, m0, m1, m2, 0.1f, 10, lA, lB);
    bin1(mm5.x, mm5.y, mm5.z, m0, m1, m2, 0.1f, 10, lA, lB);
    bin1(mm6.x, mm6.y, mm6.z, m0, m1, m2, 0.1f, 10, lA, lB);
    bin1(mm7.x, mm7.y, mm7.z, m0, m1, m2, 0.1f, 10, lA, lB);
    __syncthreads();
    u64* gA = Ap + ((size_t)c * 16 + b) * MG2;
    u64* gB = Bp + ((size_t)c * 16 + b) * MG2;
    if (tid < MG2) {
      gA[tid] = lds[tid];
      gB[tid] = lds[MG2 + tid];
    }
  }
  gridbar(bar);

  // ---- P5: reduce2 cells [c*63,+nc); chunk compact -> mc2, ccnt2 ----
  {
    int c0 = c * 63;
    int nc = (c == 15) ? (MG2 - 945) : 63;
    float4 cv = make_float4(0.f, 0.f, 0.f, 0.f);
    bool occ = false;
    if (tid < nc) {
      int cell = c0 + tid;
      u64 A = 0ull, Bv = 0ull;
#pragma unroll
      for (int p = 0; p < 16; ++p) {
        size_t o = ((size_t)p * 16 + b) * MG2 + cell;
        A += Ap[o];
        Bv += Bp[o];
      }
      u32 cnt = (u32)(Bv >> 32);
      if (cnt) {
        double inv = 1.0 / (1048576.0 * (double)cnt);
        cv.x = (float)((double)(u32)A * inv);
        cv.y = (float)((double)(u32)(A >> 32) * inv);
        cv.z = (float)((double)(u32)Bv * inv);
        occ = true;
      }
    }
    u64 mask = __ballot(occ);
    u32 wpre = (u32)__popcll(mask & ((1ull << lane) - 1ull));
    if (lane == 0) s_w[wid] = (u32)__popcll(mask);
    __syncthreads();
    if (tid == 0) {
      u32 s = 0;
      for (int w = 0; w < 16; ++w) { u32 t = s_w[w]; s_w[16 + w] = s; s += t; }
      ccnt2[b * 16 + c] = s;
    }
    __syncthreads();
    if (occ) mc2[((size_t)b * 16 + c) * 63 + s_w[16 + wid] + wpre] = cv;
  }
  gridbar(bar);

  // ---- P6: sample layer 2 (4/thread, prefix-search) ----
  {
    u32 pre[17];
    pre[0] = 0;
#pragma unroll
    for (int j = 0; j < 16; ++j) pre[j + 1] = pre[j] + ccnt2[b * 16 + j];
    u32 nv = pre[16];
    float fnv = (float)nv;
    int nvm1 = (int)nv - 1;
    uint32_t K0 = keys2.k0[b], K1 = keys2.k1[b];
    int l0 = c * 4096 + tid * 4;
    float4 sm[4];
#pragma unroll
    for (int j = 0; j < 4; ++j) {
      uint32_t w0, w1;
      tf2x32(K0, K1, 0u, (uint32_t)(l0 + j), w0, w1);
      uint32_t bits = w0 ^ w1;
      float u = __uint_as_float((bits >> 9) | 0x3F800000u) - 1.0f;
      int idx = (int)(u * fnv);
      if (idx > nvm1) idx = nvm1;
      u32 uidx = (u32)idx;
      int ch = 0, base = 0;
#pragma unroll
      for (int q = 1; q < 16; ++q) {
        u32 pq = pre[q];
        if (uidx >= pq) { ch = q; base = (int)pq; }
      }
      sm[j] = mc2[((size_t)b * 16 + ch) * 63 + (idx - base)];
    }
    float* o2 = out + (size_t)48 * ML1;
    *(float4*)(o2 + ((size_t)b * 3 + 0) * ML2 + l0) =
        make_float4(sm[0].x, sm[1].x, sm[2].x, sm[3].x);
    *(float4*)(o2 + ((size_t)b * 3 + 1) * ML2 + l0) =
        make_float4(sm[0].y, sm[1].y, sm[2].y, sm[3].y);
    *(float4*)(o2 + ((size_t)b * 3 + 2) * ML2 + l0) =
        make_float4(sm[0].z, sm[1].z, sm[2].z, sm[3].z);
  }
}

// =================== fallback multi-kernel path (atomic merge) ===================
__global__ void init_kernel(u64* cellsA, u64* cellsB, int ncells) {
  int i = blockIdx.x * blockDim.x + threadIdx.x;
  int stride = gridDim.x * blockDim.x;
  for (int j = i; j < ncells; j += stride) { cellsA[j] = 0ull; cellsB[j] = 0ull; }
}

__global__ void min_kernel(const float* __restrict__ in, int n4,
                           float* __restrict__ pmin) {
  int row = blockIdx.y;
  int PB = gridDim.x;
  const float4* p = (const float4*)in + (size_t)row * n4;
  int base = blockIdx.x * 2048 + threadIdx.x;
  float4 v0 = p[base], v1 = p[base + 256], v2 = p[base + 512],
         v3 = p[base + 768], v4 = p[base + 1024], v5 = p[base + 1280],
         v6 = p[base + 1536], v7 = p[base + 1792];
  float m0 = fminf(fminf(v0.x, v0.y), fminf(v0.z, v0.w));
  float m1 = fminf(fminf(v1.x, v1.y), fminf(v1.z, v1.w));
  float m2 = fminf(fminf(v2.x, v2.y), fminf(v2.z, v2.w));
  float m3 = fminf(fminf(v3.x, v3.y), fminf(v3.z, v3.w));
  float m4 = fminf(fminf(v4.x, v4.y), fminf(v4.z, v4.w));
  float m5 = fminf(fminf(v5.x, v5.y), fminf(v5.z, v5.w));
  float m6 = fminf(fminf(v6.x, v6.y), fminf(v6.z, v6.w));
  float m7 = fminf(fminf(v7.x, v7.y), fminf(v7.z, v7.w));
  float m = fminf(fminf(fminf(m0, m1), fminf(m2, m3)),
                  fminf(fminf(m4, m5), fminf(m6, m7)));
  for (int off = 32; off > 0; off >>= 1)
    m = fminf(m, __shfl_down(m, off, 64));
  __shared__ float wmin[4];
  int wid = threadIdx.x >> 6;
  if ((threadIdx.x & 63) == 0) wmin[wid] = m;
  __syncthreads();
  if (threadIdx.x == 0)
    pmin[row * PB + blockIdx.x] =
        fminf(fminf(wmin[0], wmin[1]), fminf(wmin[2], wmin[3]));
}

template <int G, int S>
__global__ __launch_bounds__(1024) void accum_atomic_kernel(
    const float* __restrict__ in, int N, float vox,
    const float* __restrict__ pmin, int PB, u64* __restrict__ Ap,
    u64* __restrict__ Bp) {
  extern __shared__ u64 lds[];
  u64* lA = lds;
  u64* lB = lds + G;
  __shared__ float s_m[3];
  int tid = threadIdx.x, b = blockIdx.y;
  for (int i = tid; i < G; i += 1024) { lA[i] = 0ull; lB[i] = 0ull; }
  int wid = tid >> 6, lane = tid & 63;
  if (wid < 3) {
    float v = __int_as_float(0x7F800000);
    for (int j = lane; j < PB; j += 64)
      v = fminf(v, pmin[(b * 3 + wid) * PB + j]);
    for (int off = 32; off > 0; off >>= 1)
      v = fminf(v, __shfl_down(v, off, 64));
    if (lane == 0) s_m[wid] = v;
  }
  __syncthreads();
  float m0 = s_m[0], m1 = s_m[1], m2 = s_m[2];
  int ppb = N / gridDim.x;
  const float* base = in + (size_t)b * 3 * N;
  int start = blockIdx.x * ppb;
  const float4* r0 = (const float4*)(base + start);
  const float4* r1 = (const float4*)(base + N + start);
  const float4* r2 = (const float4*)(base + 2 * N + start);
  int q4 = ppb >> 2;
  for (int i = tid; i < q4; i += 1024) {
    float4 X = r0[i], Y = r1[i], Z = r2[i];
    bin1(X.x, Y.x, Z.x, m0, m1, m2, vox, S, lA, lB);
    bin1(X.y, Y.y, Z.y, m0, m1, m2, vox, S, lA, lB);
    bin1(X.z, Y.z, Z.z, m0, m1, m2, vox, S, lA, lB);
    bin1(X.w, Y.w, Z.w, m0, m1, m2, vox, S, lA, lB);
  }
  __syncthreads();
  u64* gA = Ap + (size_t)b * G;
  u64* gB = Bp + (size_t)b * G;
  for (int cell = tid; cell < G; cell += 1024) {
    u64 Bv = lB[cell];
    if (Bv) { atomicAdd(&gA[cell], lA[cell]); atomicAdd(&gB[cell], Bv); }
  }
}

__global__ __launch_bounds__(1024) void compact_kernel(
    int G, const u64* __restrict__ Ac, const u64* __restrict__ Bc,
    float4* __restrict__ means4, u32* __restrict__ numvox) {
  int b = blockIdx.x, tid = threadIdx.x, wid = tid >> 6, lane = tid & 63;
  __shared__ u32 wtot[16], wbase[16];
  __shared__ u32 gbase;
  if (tid == 0) gbase = 0u;
  __syncthreads();
  for (int t0 = 0; t0 < G; t0 += 1024) {
    int cell = t0 + tid;
    float4 v = make_float4(0.f, 0.f, 0.f, 0.f);
    u32 cnt = 0u;
    if (cell < G) {
      u64 A = Ac[(size_t)b * G + cell], Bv = Bc[(size_t)b * G + cell];
      cnt = (u32)(Bv >> 32);
      if (cnt) {
        double inv = 1.0 / (1048576.0 * (double)cnt);
        v.x = (float)((double)(u32)A * inv);
        v.y = (float)((double)(u32)(A >> 32) * inv);
        v.z = (float)((double)(u32)Bv * inv);
      }
    }
    bool occ = cnt > 0u;
    u64 mask = __ballot(occ);
    u32 prefix = (u32)__popcll(mask & ((1ull << lane) - 1ull));
    if (lane == 0) wtot[wid] = (u32)__popcll(mask);
    __syncthreads();
    if (tid == 0) {
      u32 s = gbase;
      for (int w = 0; w < 16; ++w) { wbase[w] = s; s += wtot[w]; }
      gbase = s;
    }
    __syncthreads();
    if (occ) means4[(size_t)b * G + wbase[wid] + prefix] = v;
    __syncthreads();
  }
  if (tid == 0) numvox[b] = gbase;
}

__global__ void sample_kernel(int L, int G, const float4* __restrict__ means4,
                              const u32* __restrict__ numvox, KeyArr keys,
                              float* __restrict__ out) {
  int t = blockIdx.x * 256 + threadIdx.x;
  int b = blockIdx.y;
  int l0 = t * 4;
  u32 nv = numvox[b];
  float fnv = (float)nv;
  int nvm1 = (int)nv - 1;
  uint32_t K0 = keys.k0[b], K1 = keys.k1[b];
  float4 m[4];
#pragma unroll
  for (int j = 0; j < 4; ++j) {
    uint32_t w0, w1;
    tf2x32(K0, K1, 0u, (uint32_t)(l0 + j), w0, w1);
    uint32_t bits = w0 ^ w1;
    float u = __uint_as_float((bits >> 9) | 0x3F800000u) - 1.0f;
    int idx = (int)(u * fnv);
    if (idx > nvm1) idx = nvm1;
    m[j] = means4[(size_t)b * G + idx];
  }
  *(float4*)(out + ((size_t)b * 3 + 0) * L + l0) =
      make_float4(m[0].x, m[1].x, m[2].x, m[3].x);
  *(float4*)(out + ((size_t)b * 3 + 1) * L + l0) =
      make_float4(m[0].y, m[1].y, m[2].y, m[3].y);
  *(float4*)(out + ((size_t)b * 3 + 2) * L + l0) =
      make_float4(m[0].z, m[1].z, m[2].z, m[3].z);
}

extern "C" void kernel_launch(void* const* d_in, const int* in_sizes, int n_in,
                              void* d_out, int out_size, void* d_ws,
                              size_t ws_size, hipStream_t stream) {
  const float* x = (const float*)d_in[0];
  float* out = (float*)d_out;

  // ---- JAX key derivation (threefry partitionable split) ----
  uint32_t k1a, k1b, k2a, k2b;
  tf2x32(0u, 42u, 0u, 0u, k1a, k1b);
  tf2x32(0u, 42u, 0u, 1u, k2a, k2b);
  KeyArr keys1, keys2;
  for (int b = 0; b < 16; ++b) {
    tf2x32(k1a, k1b, 0u, (uint32_t)b, keys1.k0[b], keys1.k1[b]);
    tf2x32(k2a, k2b, 0u, (uint32_t)b, keys2.k0[b], keys2.k1[b]);
  }

  // ---- big-path workspace layout ----
  const size_t oAp = 0;
  const size_t oBp = oAp + (size_t)16 * 16 * MG1 * 8;     // 16,384,000
  const size_t oMc1 = oBp + (size_t)16 * 16 * MG1 * 8;    // 32,768,000
  const size_t oMc2 = oMc1 + (size_t)16 * 16 * 500 * 16;  // 34,816,000
  const size_t oPm1 = oMc2 + (size_t)16 * 16 * 63 * 16;   // 35,074,048
  const size_t oPm2 = oPm1 + 768 * 4;
  const size_t oCc1 = oPm2 + 768 * 4;
  const size_t oCc2 = oCc1 + 256 * 4;
  const size_t oBar = oCc2 + 256 * 4;
  const size_t bigNeed = oBar + 2048;

  uint8_t* w = (uint8_t*)d_ws;
  if (ws_size >= bigNeed) {
    u64* Ap = (u64*)(w + oAp);
    u64* Bp = (u64*)(w + oBp);
    float4* mc1 = (float4*)(w + oMc1);
    float4* mc2 = (float4*)(w + oMc2);
    float* pmin1 = (float*)(w + oPm1);
    float* pmin2 = (float*)(w + oPm2);
    u32* ccnt1 = (u32*)(w + oCc1);
    u32* ccnt2 = (u32*)(w + oCc2);
    u32* bar = (u32*)(w + oBar);
    hipMemsetAsync(bar, 0, 2048, stream);  // clean barrier state every call
    void* args[] = {(void*)&x,     (void*)&out,   (void*)&Ap,
                    (void*)&Bp,    (void*)&mc1,   (void*)&mc2,
                    (void*)&pmin1, (void*)&pmin2, (void*)&ccnt1,
                    (void*)&ccnt2, (void*)&bar,   (void*)&keys1,
                    (void*)&keys2};
    hipError_t e = hipLaunchCooperativeKernel(
        (const void*)mega2, dim3(256), dim3(1024), args, 128000, stream);
    if (e == hipSuccess) return;
    // else fall through to the non-cooperative path below
  }

  // ---- fallback: atomic-merge multi-kernel path (proven, slower) ----
  const size_t slice1 = (size_t)16 * MG1, slice2 = (size_t)16 * MG2;
  u64* As = (u64*)w;
  u64* Bs = As + (slice1 + slice2);
  float4* means4s = (float4*)(Bs + (slice1 + slice2));
  float* pmin1s = (float*)(means4s + slice1);
  float* pmin2s = pmin1s + 48 * 32;
  u32* numvoxs = (u32*)(pmin2s + 48 * 16);

  init_kernel<<<dim3(64), dim3(256), 0, stream>>>(As, Bs,
                                                  (int)(slice1 + slice2));
  min_kernel<<<dim3(32, 48), dim3(256), 0, stream>>>(x, MN1 / 4, pmin1s);
  accum_atomic_kernel<MG1, 20>
      <<<dim3(8, 16), dim3(1024), 2 * MG1 * 8, stream>>>(x, MN1, 0.05f, pmin1s,
                                                         32, As, Bs);
  compact_kernel<<<dim3(16), dim3(1024), 0, stream>>>(MG1, As, Bs, means4s,
                                                      numvoxs);
  sample_kernel<<<dim3(ML1 / 1024, 16), dim3(256), 0, stream>>>(
      ML1, MG1, means4s, numvoxs, keys1, out);
  float* out2 = out + (size_t)48 * ML1;
  min_kernel<<<dim3(16, 48), dim3(256), 0, stream>>>(out, ML1 / 4, pmin2s);
  accum_atomic_kernel<MG2, 10>
      <<<dim3(8, 16), dim3(1024), 2 * MG2 * 8, stream>>>(
          out, ML1, 0.1f, pmin2s, 16, As + slice1, Bs + slice1);
  compact_kernel<<<dim3(16), dim3(1024), 0, stream>>>(
      MG2, As + slice1, Bs + slice1, means4s, numvoxs + 16);
  sample_kernel<<<dim3(ML2 / 1024, 16), dim3(256), 0, stream>>>(
      ML2, MG2, means4s, numvoxs + 16, keys2, out2);
}

// Round 10
// 68.764 us; speedup vs baseline: 13.7779x; 13.7779x over previous
//
#include <hip/hip_runtime.h>
#include <stdint.h>

// VoxelLayer: JAX voxel-grid downsample ×2, bit-exact Threefry-2x32
// (partitionable) sampling. Round 10: revert mega-kernel (grid-sync costs
// ~100us/sync on MI355X regardless of implementation — dispatch boundaries
// are cheaper). Round-7 structure + fused reduce+chunk-compact (redcomp1)
// + prefix-search sample1. 7 dispatches.

typedef unsigned int u32;
typedef unsigned long long u64;

struct KeyArr { uint32_t k0[16]; uint32_t k1[16]; };

__host__ __device__ inline void tf2x32(uint32_t k0, uint32_t k1,
                                       uint32_t c0, uint32_t c1,
                                       uint32_t& o0, uint32_t& o1) {
  const uint32_t ks0 = k0, ks1 = k1, ks2 = k0 ^ k1 ^ 0x1BD11BDAu;
  uint32_t x0 = c0 + ks0, x1 = c1 + ks1;
#define TF_R(r) { x0 += x1; x1 = (x1 << (r)) | (x1 >> (32 - (r))); x1 ^= x0; }
  TF_R(13) TF_R(15) TF_R(26) TF_R(6)
  x0 += ks1; x1 += ks2 + 1u;
  TF_R(17) TF_R(29) TF_R(16) TF_R(24)
  x0 += ks2; x1 += ks0 + 2u;
  TF_R(13) TF_R(15) TF_R(26) TF_R(6)
  x0 += ks0; x1 += ks1 + 3u;
  TF_R(17) TF_R(29) TF_R(16) TF_R(24)
  x0 += ks1; x1 += ks2 + 4u;
  TF_R(13) TF_R(15) TF_R(26) TF_R(6)
  x0 += ks2; x1 += ks0 + 5u;
#undef TF_R
  o0 = x0; o1 = x1;
}

#define MN1 262144
#define ML1 131072
#define ML2 65536
#define MG1 8000
#define MG2 1000

__device__ __forceinline__ void bin1(float px, float py, float pz, float m0,
                                     float m1, float m2, float vox, int S,
                                     u64* lA, u64* lB) {
  int v0 = (int)floorf((px - m0) / vox);
  int v1 = (int)floorf((py - m1) / vox);
  int v2 = (int)floorf((pz - m2) / vox);
  int lin = (v0 * S + v1) * S + v2;
  u32 qx = (u32)(px * 1048576.0f);
  u32 qy = (u32)(py * 1048576.0f);
  u32 qz = (u32)(pz * 1048576.0f);
  atomicAdd(&lA[lin], ((u64)qy << 32) | (u64)qx);
  atomicAdd(&lB[lin], (1ull << 32) | (u64)qz);
}

// ---- init (small path only): zero atomic cells ----
__global__ void init_kernel(u64* cellsA, u64* cellsB, int ncells) {
  int i = blockIdx.x * blockDim.x + threadIdx.x;
  int stride = gridDim.x * blockDim.x;
  for (int j = i; j < ncells; j += stride) { cellsA[j] = 0ull; cellsB[j] = 0ull; }
}

// ---- per-(batch,coord) min: ILP-8 float4, per-block partial store ----
__global__ void min_kernel(const float* __restrict__ in, int n4,
                           float* __restrict__ pmin) {
  int row = blockIdx.y;  // b*3+c in [0,48)
  int PB = gridDim.x;
  const float4* p = (const float4*)in + (size_t)row * n4;
  int base = blockIdx.x * 2048 + threadIdx.x;
  float4 v0 = p[base], v1 = p[base + 256], v2 = p[base + 512],
         v3 = p[base + 768], v4 = p[base + 1024], v5 = p[base + 1280],
         v6 = p[base + 1536], v7 = p[base + 1792];
  float m0 = fminf(fminf(v0.x, v0.y), fminf(v0.z, v0.w));
  float m1 = fminf(fminf(v1.x, v1.y), fminf(v1.z, v1.w));
  float m2 = fminf(fminf(v2.x, v2.y), fminf(v2.z, v2.w));
  float m3 = fminf(fminf(v3.x, v3.y), fminf(v3.z, v3.w));
  float m4 = fminf(fminf(v4.x, v4.y), fminf(v4.z, v4.w));
  float m5 = fminf(fminf(v5.x, v5.y), fminf(v5.z, v5.w));
  float m6 = fminf(fminf(v6.x, v6.y), fminf(v6.z, v6.w));
  float m7 = fminf(fminf(v7.x, v7.y), fminf(v7.z, v7.w));
  float m = fminf(fminf(fminf(m0, m1), fminf(m2, m3)),
                  fminf(fminf(m4, m5), fminf(m6, m7)));
  for (int off = 32; off > 0; off >>= 1)
    m = fminf(m, __shfl_down(m, off, 64));
  __shared__ float wmin[4];
  int wid = threadIdx.x >> 6;
  if ((threadIdx.x & 63) == 0) wmin[wid] = m;
  __syncthreads();
  if (threadIdx.x == 0)
    pmin[row * PB + blockIdx.x] =
        fminf(fminf(wmin[0], wmin[1]), fminf(wmin[2], wmin[3]));
}

// ---- LDS-privatized accumulation; merge = plain store or atomic ----
template <int G, int S, bool ATOMIC>
__global__ __launch_bounds__(1024) void accum_kernel(
    const float* __restrict__ in, int N, float vox,
    const float* __restrict__ pmin, int PB, u64* __restrict__ Ap,
    u64* __restrict__ Bp) {
  extern __shared__ u64 lds[];
  u64* lA = lds;      // [G]  A = (ysum<<32)|xsum   (Q20)
  u64* lB = lds + G;  // [G]  B = (cnt <<32)|zsum
  __shared__ float s_m[3];
  int tid = threadIdx.x, b = blockIdx.y;
  for (int i = tid; i < G; i += 1024) { lA[i] = 0ull; lB[i] = 0ull; }
  int wid = tid >> 6, lane = tid & 63;
  if (wid < 3) {
    float v = __int_as_float(0x7F800000);
    for (int j = lane; j < PB; j += 64)
      v = fminf(v, pmin[(b * 3 + wid) * PB + j]);
    for (int off = 32; off > 0; off >>= 1)
      v = fminf(v, __shfl_down(v, off, 64));
    if (lane == 0) s_m[wid] = v;
  }
  __syncthreads();
  float m0 = s_m[0], m1 = s_m[1], m2 = s_m[2];
  int ppb = N / gridDim.x;
  const float* base = in + (size_t)b * 3 * N;
  int start = blockIdx.x * ppb;
  const float4* r0 = (const float4*)(base + start);
  const float4* r1 = (const float4*)(base + N + start);
  const float4* r2 = (const float4*)(base + 2 * N + start);
  int q4 = ppb >> 2;
  for (int i = tid; i < q4; i += 1024) {
    float4 X = r0[i], Y = r1[i], Z = r2[i];
    bin1(X.x, Y.x, Z.x, m0, m1, m2, vox, S, lA, lB);
    bin1(X.y, Y.y, Z.y, m0, m1, m2, vox, S, lA, lB);
    bin1(X.z, Y.z, Z.z, m0, m1, m2, vox, S, lA, lB);
    bin1(X.w, Y.w, Z.w, m0, m1, m2, vox, S, lA, lB);
  }
  __syncthreads();
  int p = ATOMIC ? 0 : blockIdx.x;
  u64* gA = Ap + ((size_t)p * 16 + b) * G;
  u64* gB = Bp + ((size_t)p * 16 + b) * G;
  for (int c = tid; c < G; c += 1024) {
    if (ATOMIC) {
      u64 Bv = lB[c];
      if (Bv) { atomicAdd(&gA[c], lA[c]); atomicAdd(&gB[c], Bv); }
    } else {
      gA[c] = lA[c];
      gB[c] = lB[c];
    }
  }
}

// ---- fused reduce(16 partials) + chunk-local compact, layer 1 ----
__global__ __launch_bounds__(512) void redcomp1_kernel(
    const u64* __restrict__ Ap, const u64* __restrict__ Bp,
    float4* __restrict__ mc1 /* [16][16][500] */, u32* __restrict__ ccnt1) {
  int c = blockIdx.x, b = blockIdx.y;
  int tid = threadIdx.x, lane = tid & 63, wid = tid >> 6;
  __shared__ u32 s_w[16];
  float4 v = make_float4(0.f, 0.f, 0.f, 0.f);
  bool occ = false;
  if (tid < 500) {
    int cell = c * 500 + tid;
    u64 A = 0ull, Bv = 0ull;
#pragma unroll
    for (int p = 0; p < 16; ++p) {
      size_t o = ((size_t)p * 16 + b) * MG1 + cell;
      A += Ap[o];
      Bv += Bp[o];
    }
    u32 cnt = (u32)(Bv >> 32);
    if (cnt) {
      double inv = 1.0 / (1048576.0 * (double)cnt);
      v.x = (float)((double)(u32)A * inv);
      v.y = (float)((double)(u32)(A >> 32) * inv);
      v.z = (float)((double)(u32)Bv * inv);
      occ = true;
    }
  }
  u64 mask = __ballot(occ);
  u32 wpre = (u32)__popcll(mask & ((1ull << lane) - 1ull));
  if (lane == 0) s_w[wid] = (u32)__popcll(mask);
  __syncthreads();
  if (tid == 0) {
    u32 s = 0;
    for (int w = 0; w < 8; ++w) { u32 t = s_w[w]; s_w[8 + w] = s; s += t; }
    ccnt1[b * 16 + c] = s;
  }
  __syncthreads();
  if (occ) mc1[((size_t)b * 16 + c) * 500 + s_w[8 + wid] + wpre] = v;
}

// ---- sample layer 1: prefix-search over 16 chunk counts; 4 outputs/thread;
//      fused layer-2 partial min (plain per-block stores) ----
__global__ void sample1_kernel(const float4* __restrict__ mc1,
                               const u32* __restrict__ ccnt1, KeyArr keys,
                               float* __restrict__ out,
                               float* __restrict__ pmin2) {
  int t = blockIdx.x * 256 + threadIdx.x;
  int b = blockIdx.y;
  int l0 = t * 4;
  u32 pre[17];
  pre[0] = 0u;
#pragma unroll
  for (int j = 0; j < 16; ++j) pre[j + 1] = pre[j] + ccnt1[b * 16 + j];
  u32 nv = pre[16];
  float fnv = (float)nv;
  int nvm1 = (int)nv - 1;
  uint32_t K0 = keys.k0[b], K1 = keys.k1[b];
  float4 m[4];
#pragma unroll
  for (int j = 0; j < 4; ++j) {
    uint32_t w0, w1;
    tf2x32(K0, K1, 0u, (uint32_t)(l0 + j), w0, w1);
    uint32_t bits = w0 ^ w1;  // partitionable fold
    float u = __uint_as_float((bits >> 9) | 0x3F800000u) - 1.0f;
    int idx = (int)(u * fnv);  // f32 RN mul, trunc
    if (idx > nvm1) idx = nvm1;
    int ch = 0;
    u32 base = 0u;
#pragma unroll
    for (int q = 1; q < 16; ++q) {
      u32 pq = pre[q];
      if ((u32)idx >= pq) { ch = q; base = pq; }
    }
    m[j] = mc1[((size_t)b * 16 + ch) * 500 + (idx - (int)base)];
  }
  *(float4*)(out + ((size_t)b * 3 + 0) * ML1 + l0) =
      make_float4(m[0].x, m[1].x, m[2].x, m[3].x);
  *(float4*)(out + ((size_t)b * 3 + 1) * ML1 + l0) =
      make_float4(m[0].y, m[1].y, m[2].y, m[3].y);
  *(float4*)(out + ((size_t)b * 3 + 2) * ML1 + l0) =
      make_float4(m[0].z, m[1].z, m[2].z, m[3].z);
  // fused next-layer partial min
  float ax = fminf(fminf(m[0].x, m[1].x), fminf(m[2].x, m[3].x));
  float ay = fminf(fminf(m[0].y, m[1].y), fminf(m[2].y, m[3].y));
  float az = fminf(fminf(m[0].z, m[1].z), fminf(m[2].z, m[3].z));
  for (int off = 32; off > 0; off >>= 1) {
    ax = fminf(ax, __shfl_down(ax, off, 64));
    ay = fminf(ay, __shfl_down(ay, off, 64));
    az = fminf(az, __shfl_down(az, off, 64));
  }
  __shared__ float wm[4][3];
  int wid = threadIdx.x >> 6;
  if ((threadIdx.x & 63) == 0) {
    wm[wid][0] = ax; wm[wid][1] = ay; wm[wid][2] = az;
  }
  __syncthreads();
  if (threadIdx.x == 0) {
    int PB = gridDim.x;
    pmin2[(b * 3 + 0) * PB + blockIdx.x] =
        fminf(fminf(wm[0][0], wm[1][0]), fminf(wm[2][0], wm[3][0]));
    pmin2[(b * 3 + 1) * PB + blockIdx.x] =
        fminf(fminf(wm[0][1], wm[1][1]), fminf(wm[2][1], wm[3][1]));
    pmin2[(b * 3 + 2) * PB + blockIdx.x] =
        fminf(fminf(wm[0][2], wm[1][2]), fminf(wm[2][2], wm[3][2]));
  }
}

// ---- fused reduce+compact for G <= 1024 (layer 2 big path) ----
template <int G>
__global__ __launch_bounds__(1024) void redcomp_kernel(
    int P, const u64* __restrict__ Ap, const u64* __restrict__ Bp,
    float4* __restrict__ means4, u32* __restrict__ numvox) {
  int b = blockIdx.x, tid = threadIdx.x, wid = tid >> 6, lane = tid & 63;
  u64 A = 0ull, Bv = 0ull;
  if (tid < G) {
    for (int p = 0; p < P; ++p) {
      size_t o = ((size_t)p * 16 + b) * G + tid;
      A += Ap[o];
      Bv += Bp[o];
    }
  }
  u32 cnt = (u32)(Bv >> 32);
  float4 v = make_float4(0.f, 0.f, 0.f, 0.f);
  if (cnt) {
    double inv = 1.0 / (1048576.0 * (double)cnt);
    v.x = (float)((double)(u32)A * inv);
    v.y = (float)((double)(u32)(A >> 32) * inv);
    v.z = (float)((double)(u32)Bv * inv);
  }
  bool occ = cnt > 0u;
  u64 mask = __ballot(occ);
  u32 prefix = (u32)__popcll(mask & ((1ull << lane) - 1ull));
  __shared__ u32 wtot[16], wbase[16];
  if (lane == 0) wtot[wid] = (u32)__popcll(mask);
  __syncthreads();
  if (tid == 0) {
    u32 s = 0;
    for (int w = 0; w < 16; ++w) { wbase[w] = s; s += wtot[w]; }
    numvox[b] = s;
  }
  __syncthreads();
  if (occ) means4[(size_t)b * G + wbase[wid] + prefix] = v;
}

// ---- direct-index sample (layer 2 / fallback); optional fused min ----
template <bool DOMIN>
__global__ void sample_kernel(int L, int G, const float4* __restrict__ means4,
                              const u32* __restrict__ numvox, KeyArr keys,
                              float* __restrict__ out,
                              float* __restrict__ pmin) {
  int t = blockIdx.x * 256 + threadIdx.x;
  int b = blockIdx.y;
  int l0 = t * 4;
  u32 nv = numvox[b];
  float fnv = (float)nv;
  int nvm1 = (int)nv - 1;
  uint32_t K0 = keys.k0[b], K1 = keys.k1[b];
  float4 m[4];
#pragma unroll
  for (int j = 0; j < 4; ++j) {
    uint32_t w0, w1;
    tf2x32(K0, K1, 0u, (uint32_t)(l0 + j), w0, w1);
    uint32_t bits = w0 ^ w1;
    float u = __uint_as_float((bits >> 9) | 0x3F800000u) - 1.0f;
    int idx = (int)(u * fnv);
    if (idx > nvm1) idx = nvm1;
    m[j] = means4[(size_t)b * G + idx];
  }
  *(float4*)(out + ((size_t)b * 3 + 0) * L + l0) =
      make_float4(m[0].x, m[1].x, m[2].x, m[3].x);
  *(float4*)(out + ((size_t)b * 3 + 1) * L + l0) =
      make_float4(m[0].y, m[1].y, m[2].y, m[3].y);
  *(float4*)(out + ((size_t)b * 3 + 2) * L + l0) =
      make_float4(m[0].z, m[1].z, m[2].z, m[3].z);
  if (DOMIN) {
    float ax = fminf(fminf(m[0].x, m[1].x), fminf(m[2].x, m[3].x));
    float ay = fminf(fminf(m[0].y, m[1].y), fminf(m[2].y, m[3].y));
    float az = fminf(fminf(m[0].z, m[1].z), fminf(m[2].z, m[3].z));
    for (int off = 32; off > 0; off >>= 1) {
      ax = fminf(ax, __shfl_down(ax, off, 64));
      ay = fminf(ay, __shfl_down(ay, off, 64));
      az = fminf(az, __shfl_down(az, off, 64));
    }
    __shared__ float wm[4][3];
    int wid = threadIdx.x >> 6;
    if ((threadIdx.x & 63) == 0) {
      wm[wid][0] = ax; wm[wid][1] = ay; wm[wid][2] = az;
    }
    __syncthreads();
    if (threadIdx.x == 0) {
      int PB = gridDim.x;
      pmin[(b * 3 + 0) * PB + blockIdx.x] =
          fminf(fminf(wm[0][0], wm[1][0]), fminf(wm[2][0], wm[3][0]));
      pmin[(b * 3 + 1) * PB + blockIdx.x] =
          fminf(fminf(wm[0][1], wm[1][1]), fminf(wm[2][1], wm[3][1]));
      pmin[(b * 3 + 2) * PB + blockIdx.x] =
          fminf(fminf(wm[0][2], wm[1][2]), fminf(wm[2][2], wm[3][2]));
    }
  }
}

// ---- serial-scan compaction (small/atomic path only) ----
__global__ __launch_bounds__(1024) void compact_kernel(
    int G, const u64* __restrict__ Ac, const u64* __restrict__ Bc,
    float4* __restrict__ means4, u32* __restrict__ numvox) {
  int b = blockIdx.x, tid = threadIdx.x, wid = tid >> 6, lane = tid & 63;
  __shared__ u32 wtot[16], wbase[16];
  __shared__ u32 gbase;
  if (tid == 0) gbase = 0u;
  __syncthreads();
  for (int t0 = 0; t0 < G; t0 += 1024) {
    int cell = t0 + tid;
    float4 v = make_float4(0.f, 0.f, 0.f, 0.f);
    u32 cnt = 0u;
    if (cell < G) {
      u64 A = Ac[(size_t)b * G + cell], Bv = Bc[(size_t)b * G + cell];
      cnt = (u32)(Bv >> 32);
      if (cnt) {
        double inv = 1.0 / (1048576.0 * (double)cnt);
        v.x = (float)((double)(u32)A * inv);
        v.y = (float)((double)(u32)(A >> 32) * inv);
        v.z = (float)((double)(u32)Bv * inv);
      }
    }
    bool occ = cnt > 0u;
    u64 mask = __ballot(occ);
    u32 prefix = (u32)__popcll(mask & ((1ull << lane) - 1ull));
    if (lane == 0) wtot[wid] = (u32)__popcll(mask);
    __syncthreads();
    if (tid == 0) {
      u32 s = gbase;
      for (int w = 0; w < 16; ++w) { wbase[w] = s; s += wtot[w]; }
      gbase = s;
    }
    __syncthreads();
    if (occ) means4[(size_t)b * G + wbase[wid] + prefix] = v;
    __syncthreads();
  }
  if (tid == 0) numvox[b] = gbase;
}

extern "C" void kernel_launch(void* const* d_in, const int* in_sizes, int n_in,
                              void* d_out, int out_size, void* d_ws,
                              size_t ws_size, hipStream_t stream) {
  const float* x = (const float*)d_in[0];
  float* out = (float*)d_out;

  // ---- JAX key derivation (threefry partitionable split) ----
  uint32_t k1a, k1b, k2a, k2b;
  tf2x32(0u, 42u, 0u, 0u, k1a, k1b);
  tf2x32(0u, 42u, 0u, 1u, k2a, k2b);
  KeyArr keys1, keys2;
  for (int b = 0; b < 16; ++b) {
    tf2x32(k1a, k1b, 0u, (uint32_t)b, keys1.k0[b], keys1.k1[b]);
    tf2x32(k2a, k2b, 0u, (uint32_t)b, keys2.k0[b], keys2.k1[b]);
  }

  const int PB1 = 32, PB2 = 128;
  // ---- big-path workspace layout ----
  const size_t oAp = 0;                                    // 16*16*8000*8
  const size_t oBp = oAp + (size_t)16 * 16 * MG1 * 8;      // = 16,384,000
  const size_t oMc1 = oBp + (size_t)16 * 16 * MG1 * 8;     // 32,768,000
  const size_t oMc2 = oMc1 + (size_t)16 * 16 * 500 * 16;   // 34,816,000
  const size_t oPm1 = oMc2 + (size_t)16 * MG2 * 16;        // 35,072,000
  const size_t oPm2 = oPm1 + 48 * PB1 * 4;
  const size_t oCc1 = oPm2 + 48 * PB2 * 4;
  const size_t oNv = oCc1 + 256 * 4;
  const size_t bigNeed = oNv + 128;

  uint8_t* w = (uint8_t*)d_ws;
  if (ws_size >= bigNeed) {
    u64* Ap = (u64*)(w + oAp);
    u64* Bp = (u64*)(w + oBp);
    float4* mc1 = (float4*)(w + oMc1);
    float4* mc2 = (float4*)(w + oMc2);
    float* pmin1 = (float*)(w + oPm1);
    float* pmin2 = (float*)(w + oPm2);
    u32* ccnt1 = (u32*)(w + oCc1);
    u32* numvox2 = (u32*)(w + oNv);

    // layer 1
    min_kernel<<<dim3(PB1, 48), dim3(256), 0, stream>>>(x, MN1 / 4, pmin1);
    accum_kernel<MG1, 20, false>
        <<<dim3(16, 16), dim3(1024), 2 * MG1 * 8, stream>>>(x, MN1, 0.05f,
                                                            pmin1, PB1, Ap, Bp);
    redcomp1_kernel<<<dim3(16, 16), dim3(512), 0, stream>>>(Ap, Bp, mc1,
                                                            ccnt1);
    sample1_kernel<<<dim3(ML1 / 1024, 16), dim3(256), 0, stream>>>(
        mc1, ccnt1, keys1, out, pmin2);
    // layer 2
    float* out2 = out + (size_t)48 * ML1;
    accum_kernel<MG2, 10, false>
        <<<dim3(16, 16), dim3(1024), 2 * MG2 * 8, stream>>>(
            out, ML1, 0.1f, pmin2, PB2, Ap, Bp);
    redcomp_kernel<MG2><<<dim3(16), dim3(1024), 0, stream>>>(16, Ap, Bp, mc2,
                                                             numvox2);
    sample_kernel<false><<<dim3(ML2 / 1024, 16), dim3(256), 0, stream>>>(
        ML2, MG2, mc2, numvox2, keys2, out2, nullptr);
    return;
  }

  // ---- fallback: atomic-merge multi-kernel path (proven, slower) ----
  const size_t slice1 = (size_t)16 * MG1, slice2 = (size_t)16 * MG2;
  u64* As = (u64*)w;
  u64* Bs = As + (slice1 + slice2);
  float4* means4s = (float4*)(Bs + (slice1 + slice2));
  float* pmin1s = (float*)(means4s + slice1);
  float* pmin2s = pmin1s + 48 * PB1;
  u32* numvoxs = (u32*)(pmin2s + 48 * PB2);

  init_kernel<<<dim3(64), dim3(256), 0, stream>>>(As, Bs,
                                                  (int)(slice1 + slice2));
  min_kernel<<<dim3(PB1, 48), dim3(256), 0, stream>>>(x, MN1 / 4, pmin1s);
  accum_kernel<MG1, 20, true>
      <<<dim3(8, 16), dim3(1024), 2 * MG1 * 8, stream>>>(x, MN1, 0.05f, pmin1s,
                                                         PB1, As, Bs);
  compact_kernel<<<dim3(16), dim3(1024), 0, stream>>>(MG1, As, Bs, means4s,
                                                      numvoxs);
  sample_kernel<true><<<dim3(ML1 / 1024, 16), dim3(256), 0, stream>>>(
      ML1, MG1, means4s, numvoxs, keys1, out, pmin2s);
  float* out2 = out + (size_t)48 * ML1;
  accum_kernel<MG2, 10, true>
      <<<dim3(8, 16), dim3(1024), 2 * MG2 * 8, stream>>>(
          out, ML1, 0.1f, pmin2s, PB2, As + slice1, Bs + slice1);
  compact_kernel<<<dim3(16), dim3(1024), 0, stream>>>(
      MG2, As + slice1, Bs + slice1, means4s, numvoxs + 16);
  sample_kernel<false><<<dim3(ML2 / 1024, 16), dim3(256), 0, stream>>>(
      ML2, MG2, means4s, numvoxs + 16, keys2, out2, nullptr);
}